// Round 4
// baseline (701.080 us; speedup 1.0000x reference)
//
#include <hip/hip_runtime.h>
#include <math.h>

#define BATCH   2097152
#define NTILES  (BATCH / 16)
#define GRID    2048
#define BLOCK   256
#define WPB     (BLOCK / 64)
#define WAVES   (GRID * WPB)
#define NREP    16
#define NSETS   8

typedef __attribute__((ext_vector_type(8))) short short8;   // 8 bf16 = 4 VGPRs (MFMA A/B frag)
typedef __attribute__((ext_vector_type(4))) float f32x4;    // MFMA C/D frag
typedef unsigned short ushort_t;

// Orientation: transposed products D^T = W^T X^T.
//   A-operand = W^T via wfrag: lane(m=lane&15,q) reg j = W[k=q*8+j][m+16*half].
//   B-operand = X^T: lane(n=lane&15=batch,q) reg j = X[batch n][ch q*8+j]
//     -> EXACTLY a batch-major 16B row segment: load h directly, no shuffles.
//   C/D: col=lane&15=batch m, row=q*4+r (+16 per frag) = channel.  [verified r2]
// h stored batch-major bf16 [row][32ch]: C-layout stores = two contiguous 8B stores.

__device__ __forceinline__ float silu_f(float x) {
    return x * __builtin_amdgcn_rcpf(1.0f + __expf(-x));
}
__device__ __forceinline__ unsigned short f2bf(float f) {   // fp32 -> bf16 RTNE
    union { float f; unsigned u; } v; v.f = f;
    unsigned r = v.u + 0x7fffu + ((v.u >> 16) & 1u);
    return (unsigned short)(r >> 16);
}
__device__ __forceinline__ unsigned pkbf(float a, float b) {
    return (unsigned)f2bf(a) | ((unsigned)f2bf(b) << 16);
}
__device__ __forceinline__ float bflo(unsigned u) {
    union { unsigned u; float f; } v; v.u = u << 16; return v.f;
}
__device__ __forceinline__ float bfhi(unsigned u) {
    union { unsigned u; float f; } v; v.u = u & 0xffff0000u; return v.f;
}
__device__ __forceinline__ f32x4 mfma16(short8 a, short8 b, f32x4 c) {
    return __builtin_amdgcn_mfma_f32_16x16x32_bf16(a, b, c, 0, 0, 0);
}
// W^T as A-operand: lane(m,q) reg j holds W[k=q*8+j][(lane&15)+16*half].
__device__ __forceinline__ short8 wfrag(const float* W, int ldN, int K, int lane, int half, int N) {
    short8 r;
    const int n = (lane & 15) + 16 * half;
    const int k0 = (lane >> 4) * 8;
    #pragma unroll
    for (int j = 0; j < 8; ++j) {
        const int k = k0 + j;
        const float v = (k < K && n < N) ? W[k * ldN + n] : 0.f;
        ((unsigned short*)&r)[j] = f2bf(v);
    }
    return r;
}
// C-layout (lane m=batch, q: chans {4q..4q+3, 16+4q..16+4q+3} packed in pk.xyzw)
//   -> B-operand (lane m=batch, q: chans q*8..q*8+7).
// ds_bpermute pulls the SOURCE lane's data; select dest-side on returned values.
__device__ __forceinline__ short8 c2b(uint4 pk, int addrA, int addrB, int hi) {
    const int xA = __builtin_amdgcn_ds_bpermute(addrA, (int)pk.x);
    const int yA = __builtin_amdgcn_ds_bpermute(addrA, (int)pk.y);
    const int zA = __builtin_amdgcn_ds_bpermute(addrA, (int)pk.z);
    const int wA = __builtin_amdgcn_ds_bpermute(addrA, (int)pk.w);
    const int xB = __builtin_amdgcn_ds_bpermute(addrB, (int)pk.x);
    const int yB = __builtin_amdgcn_ds_bpermute(addrB, (int)pk.y);
    const int zB = __builtin_amdgcn_ds_bpermute(addrB, (int)pk.z);
    const int wB = __builtin_amdgcn_ds_bpermute(addrB, (int)pk.w);
    union { int d[4]; short8 s; } u;
    u.d[0] = hi ? zA : xA;
    u.d[1] = hi ? wA : yA;
    u.d[2] = hi ? zB : xB;
    u.d[3] = hi ? wB : yB;
    return u.s;
}
// BN folded coefs from replicated fp64 sums: y = A*x + C
__device__ __forceinline__ void bn_coef(const double* sIn, const float* g, const float* b,
                                        int c, float* A, float* C) {
    double s = 0, q = 0;
    #pragma unroll
    for (int r = 0; r < NREP; ++r) { s += sIn[r * 64 + c]; q += sIn[r * 64 + 32 + c]; }
    const double inv = 1.0 / (double)BATCH;
    const double mu = s * inv, var = q * inv - mu * mu;
    const float a = (float)(1.0 / sqrt(var + 1e-5)) * g[c];
    *A = a; *C = b[c] - (float)mu * a;
}
// Stats over C-layout accumulators: element e = channel (e<4 ? q*4+e : 16+q*4+e-4),
// summed over batch (m bits 0..3 of lane). Wave-reduce over m, then block+atomic.
__device__ __forceinline__ void stats_reduce_t(float* sS, float* sQ,
        float (*sRed)[64], double* sOut, int tid)
{
    const int lane = tid & 63, wid = tid >> 6, q = (lane >> 4) & 3;
    #pragma unroll
    for (int e = 0; e < 8; ++e) {
        float s = sS[e], v = sQ[e];
        #pragma unroll
        for (int mk = 1; mk <= 8; mk <<= 1) {
            s += __shfl_xor(s, mk, 64);
            v += __shfl_xor(v, mk, 64);
        }
        sS[e] = s; sQ[e] = v;
    }
    if ((lane & 15) == 0) {
        #pragma unroll
        for (int e = 0; e < 8; ++e) {
            const int ch = (e < 4) ? (q * 4 + e) : (16 + q * 4 + (e - 4));
            sRed[wid][ch] = sS[e];
            sRed[wid][32 + ch] = sQ[e];
        }
    }
    __syncthreads();
    if (tid < 64) {
        const float tot = sRed[0][tid] + sRed[1][tid] + sRed[2][tid] + sRed[3][tid];
        atomicAdd(sOut + tid, (double)tot);
    }
}

// ---- Fold rfft -> complex mix -> irfft into one real 32x32 matrix per layer (+I skip) ----
__global__ void setup_f_kernel(const float* __restrict__ wr, const float* __restrict__ wi,
                               float* __restrict__ Fp)
{
    __shared__ double cs[32], sn[32];
    const int l = blockIdx.x, tid = threadIdx.x;
    if (tid < 32) {
        double a = (2.0 * 3.14159265358979323846 / 32.0) * (double)tid;
        cs[tid] = cos(a); sn[tid] = sin(a);
    }
    __syncthreads();
    const float* wrl = wr + l * 289;
    const float* wil = wi + l * 289;
    for (int p = tid; p < 1024; p += BLOCK) {
        const int d = p >> 5, j = p & 31;
        double acc = 0.0;
        for (int m = 0; m < 17; ++m) {
            double yr = 0.0, yi = 0.0;
            for (int k = 0; k < 17; ++k) {
                const double c = cs[(k * d) & 31], s = sn[(k * d) & 31];
                const double a = (double)wrl[k * 17 + m], b = (double)wil[k * 17 + m];
                yr += c * a + s * b;
                yi += c * b - s * a;
            }
            const double alpha = (m == 0 || m == 16) ? 1.0 : 2.0;
            acc += alpha * (cs[(j * m) & 31] * yr - sn[(j * m) & 31] * yi);
        }
        const double F = acc * (1.0 / 32.0);
        Fp[l * 1024 + d * 32 + j] = (float)(F + ((d == j) ? 1.0 : 0.0));
    }
}

// ---- stem: h^T = sw^T x^T + sb ; store batch-major bf16; stats(h) ----
__global__ __launch_bounds__(BLOCK) void stem_kernel(
    const float* __restrict__ x, const float* __restrict__ sw, const float* __restrict__ sb,
    ushort_t* __restrict__ h, double* __restrict__ sOut)
{
    __shared__ float sRed[WPB][64];
    const int tid = threadIdx.x, lane = tid & 63, wid = tid >> 6;
    const int m = lane & 15, q = lane >> 4;
    const short8 A0 = wfrag(sw, 32, 10, lane, 0, 32);
    const short8 A1 = wfrag(sw, 32, 10, lane, 1, 32);
    float bk[8];
    #pragma unroll
    for (int e = 0; e < 8; ++e)
        bk[e] = sb[(e < 4) ? (q * 4 + e) : (16 + q * 4 + (e - 4))];
    float sS[8], sQ[8];
    #pragma unroll
    for (int e = 0; e < 8; ++e) { sS[e] = 0.f; sQ[e] = 0.f; }
    for (int t = blockIdx.x * WPB + wid; t < NTILES; t += WAVES) {
        const size_t rb = (size_t)t * 16;
        // B-frag of x^T directly from global: element j = x[batch m][k=q*8+j] (k<10)
        float xv[8];
        #pragma unroll
        for (int e = 0; e < 8; ++e) xv[e] = 0.f;
        const float* xr = x + (rb + m) * 10;
        if (q == 0) {
            #pragma unroll
            for (int a = 0; a < 4; ++a) {
                const float2 v = *(const float2*)(xr + 2 * a);
                xv[2 * a] = v.x; xv[2 * a + 1] = v.y;
            }
        } else if (q == 1) {
            const float2 v = *(const float2*)(xr + 8);
            xv[0] = v.x; xv[1] = v.y;
        }
        short8 xB;
        #pragma unroll
        for (int e = 0; e < 8; ++e) ((unsigned short*)&xB)[e] = f2bf(xv[e]);
        f32x4 c0, c1;
        #pragma unroll
        for (int r = 0; r < 4; ++r) { c0[r] = bk[r]; c1[r] = bk[4 + r]; }
        c0 = mfma16(A0, xB, c0);
        c1 = mfma16(A1, xB, c1);
        float hn[8];
        #pragma unroll
        for (int r = 0; r < 4; ++r) { hn[r] = c0[r]; hn[4 + r] = c1[r]; }
        #pragma unroll
        for (int e = 0; e < 8; ++e) { sS[e] += hn[e]; sQ[e] += hn[e] * hn[e]; }
        uint2 lo, hi2;
        lo.x  = pkbf(hn[0], hn[1]); lo.y  = pkbf(hn[2], hn[3]);
        hi2.x = pkbf(hn[4], hn[5]); hi2.y = pkbf(hn[6], hn[7]);
        ushort_t* hr = h + (rb + m) * 32;
        *(uint2*)(hr + q * 4)      = lo;    // ch 4q..4q+3 of batch m
        *(uint2*)(hr + 16 + q * 4) = hi2;   // ch 16+4q..16+4q+3
    }
    stats_reduce_t(sS, sQ, sRed, sOut + (size_t)(blockIdx.x & (NREP - 1)) * 64, tid);
}

// ---- P1: stats of r1 = silu(bn1(h)) @ W1 + lb1 (zero cross-lane) ----
__global__ __launch_bounds__(BLOCK) void p1_kernel(
    const ushort_t* __restrict__ h_in, const double* __restrict__ sIn, double* __restrict__ sOut,
    const float* __restrict__ g1, const float* __restrict__ b1,
    const float* __restrict__ w1, const float* __restrict__ lb1)
{
    __shared__ float cA[32], cC[32];
    __shared__ float sRed[WPB][64];
    const int tid = threadIdx.x, lane = tid & 63, wid = tid >> 6;
    if (tid < 32) bn_coef(sIn, g1, b1, tid, &cA[tid], &cC[tid]);
    __syncthreads();
    const int m = lane & 15, q = lane >> 4;
    const short8 W1T0 = wfrag(w1, 32, 32, lane, 0, 32);
    const short8 W1T1 = wfrag(w1, 32, 32, lane, 1, 32);
    float a1k[8], c1k[8], lbk[8];
    #pragma unroll
    for (int j = 0; j < 8; ++j) { a1k[j] = cA[q * 8 + j]; c1k[j] = cC[q * 8 + j]; } // B-layout ch
    #pragma unroll
    for (int e = 0; e < 8; ++e)
        lbk[e] = lb1[(e < 4) ? (q * 4 + e) : (16 + q * 4 + (e - 4))];               // C-layout ch
    float sS[8], sQ[8];
    #pragma unroll
    for (int e = 0; e < 8; ++e) { sS[e] = 0.f; sQ[e] = 0.f; }
    for (int t = blockIdx.x * WPB + wid; t < NTILES; t += WAVES) {
        const size_t rb = (size_t)t * 16;
        const short8 hB = *(const short8*)(h_in + (rb + m) * 32 + q * 8); // direct B-frag
        float tv[8];
        #pragma unroll
        for (int j = 0; j < 8; ++j) {
            const float hv = bflo(((const unsigned short*)&hB)[j] << 0) // placeholder
                ;
            (void)hv;
        }
        #pragma unroll
        for (int j = 0; j < 8; ++j) {
            union { unsigned u; float f; } v;
            v.u = ((unsigned)((const unsigned short*)&hB)[j]) << 16;
            tv[j] = silu_f(fmaf(a1k[j], v.f, c1k[j]));
        }
        short8 tB;
        #pragma unroll
        for (int j = 0; j < 8; ++j) ((unsigned short*)&tB)[j] = f2bf(tv[j]);
        const f32x4 z = {0.f, 0.f, 0.f, 0.f};
        const f32x4 r0 = mfma16(W1T0, tB, z);
        const f32x4 r1 = mfma16(W1T1, tB, z);
        #pragma unroll
        for (int r = 0; r < 4; ++r) {
            const float v0 = r0[r] + lbk[r];
            const float v1 = r1[r] + lbk[4 + r];
            sS[r] += v0;     sQ[r] += v0 * v0;
            sS[4 + r] += v1; sQ[4 + r] += v1 * v1;
        }
    }
    stats_reduce_t(sS, sQ, sRed, sOut + (size_t)(blockIdx.x & (NREP - 1)) * 64, tid);
}

// ---- P2: h_new^T = silu(Fp^T h^T + W2^T silu(bn2(W1^T t^T)) + b2); stats or head ----
template<bool LAST>
__global__ __launch_bounds__(BLOCK) void p2_kernel(
    const ushort_t* __restrict__ h_in, ushort_t* __restrict__ h_out, float* __restrict__ out,
    const double* __restrict__ sIn1, const double* __restrict__ sIn2, double* __restrict__ sOut,
    const float* __restrict__ g1, const float* __restrict__ b1,
    const float* __restrict__ w1, const float* __restrict__ lb1,
    const float* __restrict__ g2, const float* __restrict__ b2,
    const float* __restrict__ w2, const float* __restrict__ lb2,
    const float* __restrict__ Fp, const float* __restrict__ hw, const float* __restrict__ hb)
{
    __shared__ float cA1[32], cC1[32], cA2[32], cD2[32];
    __shared__ float sRed[WPB][64];
    const int tid = threadIdx.x, lane = tid & 63, wid = tid >> 6;
    if (tid < 32) {
        bn_coef(sIn1, g1, b1, tid, &cA1[tid], &cC1[tid]);
    } else if (tid < 64) {
        const int c = tid - 32;
        float A, C;
        bn_coef(sIn2, g2, b2, c, &A, &C);
        cA2[c] = A; cD2[c] = C + A * lb1[c];   // fold lb1 into bn2 offset
    }
    __syncthreads();
    const int m = lane & 15, q = lane >> 4;
    const int addrA = 4 * (m + 32 * (q & 1)), addrB = addrA + 64, hi = q >> 1;
    const short8 W1T0 = wfrag(w1, 32, 32, lane, 0, 32);
    const short8 W1T1 = wfrag(w1, 32, 32, lane, 1, 32);
    const short8 W2T0 = wfrag(w2, 32, 32, lane, 0, 32);
    const short8 W2T1 = wfrag(w2, 32, 32, lane, 1, 32);
    const short8 FT0  = wfrag(Fp, 32, 32, lane, 0, 32);
    const short8 FT1  = wfrag(Fp, 32, 32, lane, 1, 32);
    float a1k[8], c1k[8];                       // B-layout ch = q*8+j
    #pragma unroll
    for (int j = 0; j < 8; ++j) { a1k[j] = cA1[q * 8 + j]; c1k[j] = cC1[q * 8 + j]; }
    float a2k[8], d2k[8], b2k[8];               // C-layout ch
    #pragma unroll
    for (int e = 0; e < 8; ++e) {
        const int ch = (e < 4) ? (q * 4 + e) : (16 + q * 4 + (e - 4));
        a2k[e] = cA2[ch]; d2k[e] = cD2[ch]; b2k[e] = lb2[ch];
    }
    short8 HWT = {};
    float hbk[4] = {0.f, 0.f, 0.f, 0.f};
    if (LAST) {
        HWT = wfrag(hw, 10, 32, lane, 0, 10);
        #pragma unroll
        for (int r = 0; r < 4; ++r) hbk[r] = (q * 4 + r < 10) ? hb[q * 4 + r] : 0.f;
    }
    float sS[8], sQ[8];
    #pragma unroll
    for (int e = 0; e < 8; ++e) { sS[e] = 0.f; sQ[e] = 0.f; }

    for (int t = blockIdx.x * WPB + wid; t < NTILES; t += WAVES) {
        const size_t rb = (size_t)t * 16;
        const short8 hB = *(const short8*)(h_in + (rb + m) * 32 + q * 8); // direct B-frag
        float tv[8];
        #pragma unroll
        for (int j = 0; j < 8; ++j) {
            union { unsigned u; float f; } v;
            v.u = ((unsigned)((const unsigned short*)&hB)[j]) << 16;
            tv[j] = silu_f(fmaf(a1k[j], v.f, c1k[j]));
        }
        short8 tB;
        #pragma unroll
        for (int j = 0; j < 8; ++j) ((unsigned short*)&tB)[j] = f2bf(tv[j]);
        const f32x4 z = {0.f, 0.f, 0.f, 0.f};
        const f32x4 r0 = mfma16(W1T0, tB, z);
        const f32x4 r1 = mfma16(W1T1, tB, z);
        float uv[8];
        #pragma unroll
        for (int r = 0; r < 4; ++r) {
            uv[r]     = silu_f(fmaf(a2k[r], r0[r], d2k[r]));
            uv[4 + r] = silu_f(fmaf(a2k[4 + r], r1[r], d2k[4 + r]));
        }
        uint4 up;
        up.x = pkbf(uv[0], uv[1]); up.y = pkbf(uv[2], uv[3]);
        up.z = pkbf(uv[4], uv[5]); up.w = pkbf(uv[6], uv[7]);
        const short8 uB = c2b(up, addrA, addrB, hi);
        f32x4 c0, c1;
        #pragma unroll
        for (int r = 0; r < 4; ++r) { c0[r] = b2k[r]; c1[r] = b2k[4 + r]; }
        c0 = mfma16(FT0, hB, c0);  c1 = mfma16(FT1, hB, c1);
        c0 = mfma16(W2T0, uB, c0); c1 = mfma16(W2T1, uB, c1);
        float hn[8];
        #pragma unroll
        for (int r = 0; r < 4; ++r) { hn[r] = silu_f(c0[r]); hn[4 + r] = silu_f(c1[r]); }
        uint4 np;
        np.x = pkbf(hn[0], hn[1]); np.y = pkbf(hn[2], hn[3]);
        np.z = pkbf(hn[4], hn[5]); np.w = pkbf(hn[6], hn[7]);
        if (!LAST) {
            #pragma unroll
            for (int e = 0; e < 8; ++e) { sS[e] += hn[e]; sQ[e] += hn[e] * hn[e]; }
            ushort_t* hr = h_out + (rb + m) * 32;
            *(uint2*)(hr + q * 4)      = *(uint2*)&np.x;
            *(uint2*)(hr + 16 + q * 4) = *(uint2*)&np.z;
        } else {
            const short8 nB = c2b(np, addrA, addrB, hi);
            f32x4 oc;
            #pragma unroll
            for (int r = 0; r < 4; ++r) oc[r] = hbk[r];
            oc = mfma16(HWT, nB, oc);   // out^T: row=out-ch q*4+r, col=batch m
            #pragma unroll
            for (int r = 0; r < 4; ++r)
                if (q * 4 + r < 10) out[(rb + m) * 10 + q * 4 + r] = oc[r];
        }
    }
    if (!LAST)
        stats_reduce_t(sS, sQ, sRed, sOut + (size_t)(blockIdx.x & (NREP - 1)) * 64, tid);
}

extern "C" void kernel_launch(void* const* d_in, const int* in_sizes, int n_in,
                              void* d_out, int out_size, void* d_ws, size_t ws_size,
                              hipStream_t stream)
{
    const float* x      = (const float*)d_in[0];
    const float* stem_w = (const float*)d_in[1];
    const float* stem_b = (const float*)d_in[2];
    const float* fno_wr = (const float*)d_in[3];
    const float* fno_wi = (const float*)d_in[4];
    const float* bn1_g  = (const float*)d_in[5];
    const float* bn1_b  = (const float*)d_in[6];
    const float* lin1_w = (const float*)d_in[7];
    const float* lin1_b = (const float*)d_in[8];
    const float* bn2_g  = (const float*)d_in[9];
    const float* bn2_b  = (const float*)d_in[10];
    const float* lin2_w = (const float*)d_in[11];
    const float* lin2_b = (const float*)d_in[12];
    const float* head_w = (const float*)d_in[13];
    const float* head_b = (const float*)d_in[14];

    // workspace: [ h (B*32 bf16, 128 MiB) | Fp (4*1024 f32) | stats (8 sets * 16 reps * 64 f64) ]
    ushort_t* h  = (ushort_t*)d_ws;
    float*    Fp = (float*)((char*)d_ws + (size_t)BATCH * 32 * sizeof(ushort_t));
    double*   st = (double*)((char*)d_ws + (size_t)BATCH * 32 * sizeof(ushort_t) + 16384);

    hipMemsetAsync(st, 0, (size_t)NSETS * NREP * 64 * sizeof(double), stream);
    setup_f_kernel<<<4, BLOCK, 0, stream>>>(fno_wr, fno_wi, Fp);
    stem_kernel<<<GRID, BLOCK, 0, stream>>>(x, stem_w, stem_b, h, st);

    for (int l = 0; l < 4; ++l) {
        double* sH = st + (size_t)(2 * l) * NREP * 64;
        double* sR = st + (size_t)(2 * l + 1) * NREP * 64;
        p1_kernel<<<GRID, BLOCK, 0, stream>>>(
            h, sH, sR,
            bn1_g + l * 32, bn1_b + l * 32, lin1_w + l * 1024, lin1_b + l * 32);
        if (l < 3) {
            double* sN = st + (size_t)(2 * l + 2) * NREP * 64;
            p2_kernel<false><<<GRID, BLOCK, 0, stream>>>(
                h, h, nullptr, sH, sR, sN,
                bn1_g + l * 32, bn1_b + l * 32, lin1_w + l * 1024, lin1_b + l * 32,
                bn2_g + l * 32, bn2_b + l * 32, lin2_w + l * 1024, lin2_b + l * 32,
                Fp + l * 1024, nullptr, nullptr);
        } else {
            p2_kernel<true><<<GRID, BLOCK, 0, stream>>>(
                h, nullptr, (float*)d_out, sH, sR, nullptr,
                bn1_g + l * 32, bn1_b + l * 32, lin1_w + l * 1024, lin1_b + l * 32,
                bn2_g + l * 32, bn2_b + l * 32, lin2_w + l * 1024, lin2_b + l * 32,
                Fp + l * 1024, head_w, head_b);
        }
    }
}